// Round 1
// baseline (1591.884 us; speedup 1.0000x reference)
//
#include <hip/hip_runtime.h>
#include <math.h>

// ---------------------------------------------------------------------------
// Setup kernel: build the weighted CG contraction tensor C[9][9][9] on device
// from tp_w (11 path weights), replicating the reference's _w3j + scaling.
// Runs once per launch, 1 block x 64 threads, ~tens of microseconds.
// ---------------------------------------------------------------------------

struct cd_t { double re, im; };
__device__ inline cd_t cmul(cd_t a, cd_t b) {
    return { a.re * b.re - a.im * b.im, a.re * b.im + a.im * b.re };
}

__device__ inline double dfact(int n) {
    double r = 1.0;
    for (int i = 2; i <= n; ++i) r *= (double)i;
    return r;
}

__device__ double su2cg(int j1, int j2, int j3, int m1, int m2, int m3) {
    if (m1 + m2 != m3) return 0.0;
    double pre = sqrt((2.0 * j3 + 1.0) * dfact(j3 + j1 - j2) * dfact(j3 - j1 + j2) * dfact(j1 + j2 - j3)
                      * dfact(j3 + m3) * dfact(j3 - m3)
                      / (dfact(j1 + j2 + j3 + 1) * dfact(j1 - m1) * dfact(j1 + m1)
                         * dfact(j2 - m2) * dfact(j2 + m2)));
    double S = 0.0;
    for (int v = 0; v <= j1 + j2 + j3; ++v) {
        int b1 = j3 - j1 + j2 - v;
        int b2 = j3 + m3 - v;
        int b3 = v + j1 - j2 - m3;
        int b4 = j2 + j3 + m1 - v;
        int b5 = j1 - m1 + v;
        if (b1 < 0 || b2 < 0 || b3 < 0 || b4 < 0 || b5 < 0) continue;
        double term = dfact(b4) * dfact(b5) / (dfact(v) * dfact(b1) * dfact(b2) * dfact(b3));
        S += ((v + j2 + m2) & 1) ? -term : term;
    }
    return pre * S;
}

__device__ void qmat(int l, cd_t q[5][5]) {
    for (int r = 0; r < 5; ++r)
        for (int c = 0; c < 5; ++c) q[r][c] = { 0.0, 0.0 };
    double s = 1.0 / sqrt(2.0);
    for (int m = -l; m < 0; ++m) {
        q[l + m][l - m] = { s, 0.0 };     // col l+|m|
        q[l + m][l + m] = { 0.0, -s };    // col l-|m|
    }
    q[l][l] = { 1.0, 0.0 };
    for (int m = 1; m <= l; ++m) {
        double sg = (m & 1) ? -1.0 : 1.0;
        q[l + m][l + m] = { sg * s, 0.0 };
        q[l + m][l - m] = { 0.0, sg * s };
    }
    // multiply by (-i)^l
    cd_t ph = (l == 0) ? cd_t{ 1.0, 0.0 } : (l == 1) ? cd_t{ 0.0, -1.0 } : cd_t{ -1.0, 0.0 };
    for (int r = 0; r < 5; ++r)
        for (int c = 0; c < 5; ++c) q[r][c] = cmul(ph, q[r][c]);
}

__device__ const int PA[11] = { 0,0,0,1,1,1,1,2,2,2,2 };
__device__ const int PB[11] = { 0,1,2,0,1,1,2,0,1,2,2 };
__device__ const int PC[11] = { 0,1,2,1,0,2,1,2,1,0,2 };
__device__ const double FANIN[3] = { 3.0, 4.0, 4.0 };

__global__ void setup_C_kernel(const float* __restrict__ tpw, float* __restrict__ Cd) {
    int t = threadIdx.x;
    for (int u = t; u < 729; u += 64) Cd[u] = 0.0f;
    __syncthreads();
    if (t >= 11) return;

    int a = PA[t], b = PB[t], c = PC[t];
    int na = 2 * a + 1, nb = 2 * b + 1, nc = 2 * c + 1;

    // complex-basis CG values: for (i,k) the only nonzero n is c + (i-a)+(k-b)
    double cg2[5][5];
    for (int i = 0; i < na; ++i)
        for (int k = 0; k < nb; ++k) {
            int m3 = (i - a) + (k - b);
            cg2[i][k] = (m3 >= -c && m3 <= c) ? su2cg(a, b, c, i - a, k - b, m3) : 0.0;
        }

    cd_t Q1[5][5], Q2[5][5], Q3[5][5];
    qmat(a, Q1); qmat(b, Q2); qmat(c, Q3);

    // R[j][l][m] = Re( sum_{i,k} Q1[i][j] Q2[k][l] conj(Q3[n][m]) cg2[i][k] )
    double R[5][5][5];
    double nrm = 0.0;
    for (int j = 0; j < na; ++j)
        for (int l = 0; l < nb; ++l)
            for (int m = 0; m < nc; ++m) {
                double re = 0.0;
                for (int i = 0; i < na; ++i)
                    for (int k = 0; k < nb; ++k) {
                        double g = cg2[i][k];
                        if (g == 0.0) continue;
                        int n = (i - a) + (k - b) + c;
                        cd_t tt = cmul(Q1[i][j], Q2[k][l]);
                        cd_t q3 = { Q3[n][m].re, -Q3[n][m].im };
                        tt = cmul(tt, q3);
                        re += tt.re * g;
                    }
                R[j][l][m] = re;
                nrm += re * re;
            }

    double sc = (double)tpw[t] * sqrt((double)nc / FANIN[c]) / sqrt(nrm);
    for (int j = 0; j < na; ++j)
        for (int l = 0; l < nb; ++l)
            for (int m = 0; m < nc; ++m)
                Cd[(a * a + j) * 81 + (b * b + l) * 9 + (c * c + m)] = (float)(sc * R[j][l][m]);
}

// ---------------------------------------------------------------------------
// Main kernel: streaming fused TP + linear. V items (e,c pairs) per thread.
// ---------------------------------------------------------------------------

#define TPV 4   // items per thread (9*TPV floats per buffer, must keep 16B align: 9*TPV%4==0)

// allowed output-c blocks per (a,b) input block pair (bitmask over c=0,1,2)
__device__ constexpr int ALLOWC[3][3] = { {1, 2, 4}, {2, 5, 2}, {4, 2, 5} };

__global__ __launch_bounds__(256) void tp_main_kernel(
        const float* __restrict__ x, const float* __restrict__ y,
        float* __restrict__ out,
        const float* __restrict__ Cg,
        const float* __restrict__ Wfx, const float* __restrict__ bfx,
        const float* __restrict__ Wfy, const float* __restrict__ bfy,
        long n_items) {
    __shared__ float Cl[729];
    __shared__ float Wxs[81];
    __shared__ float Wys[81];
    __shared__ float bs[9];

    int t = threadIdx.x;
    for (int u = t; u < 729; u += 256) Cl[u] = Cg[u];
    if (t < 81) { Wxs[t] = Wfx[t]; Wys[t] = Wfy[t]; }
    if (t < 9)  { bs[t] = bfx[t] + bfy[t]; }
    __syncthreads();

    long set = (long)blockIdx.x * blockDim.x + t;
    long item0 = set * TPV;
    if (item0 >= n_items) return;

    const float4* x4 = reinterpret_cast<const float4*>(x) + set * (9 * TPV / 4);
    const float4* y4 = reinterpret_cast<const float4*>(y) + set * (9 * TPV / 4);
    float4* o4 = reinterpret_cast<float4*>(out) + set * (9 * TPV / 4);

    float xs[9 * TPV], ys[9 * TPV], os[9 * TPV];

    #pragma unroll
    for (int q = 0; q < 9 * TPV / 4; ++q) {
        float4 tx = x4[q];
        xs[q * 4 + 0] = tx.x; xs[q * 4 + 1] = tx.y; xs[q * 4 + 2] = tx.z; xs[q * 4 + 3] = tx.w;
        float4 ty = y4[q];
        ys[q * 4 + 0] = ty.x; ys[q * 4 + 1] = ty.y; ys[q * 4 + 2] = ty.z; ys[q * 4 + 3] = ty.w;
    }

    // init with biases
    #pragma unroll
    for (int k = 0; k < 9; ++k) {
        float b = bs[k];
        #pragma unroll
        for (int v = 0; v < TPV; ++v) os[v * 9 + k] = b;
    }

    // linear branches: out_k += sum_i Wfx[k,i]*x_i + Wfy[k,i]*y_i
    #pragma unroll
    for (int k = 0; k < 9; ++k) {
        #pragma unroll
        for (int i = 0; i < 9; ++i) {
            float wx = Wxs[k * 9 + i];
            float wy = Wys[k * 9 + i];
            #pragma unroll
            for (int v = 0; v < TPV; ++v)
                os[v * 9 + k] += wx * xs[v * 9 + i] + wy * ys[v * 9 + i];
        }
    }

    // tensor product: only (a,b,c) blocks allowed by selection rules
    #pragma unroll
    for (int a = 0; a < 3; ++a) {
        #pragma unroll
        for (int b = 0; b < 3; ++b) {
            #pragma unroll
            for (int di = 0; di < 2 * a + 1; ++di) {
                #pragma unroll
                for (int dj = 0; dj < 2 * b + 1; ++dj) {
                    const int i = a * a + di;
                    const int j = b * b + dj;
                    float p[TPV];
                    #pragma unroll
                    for (int v = 0; v < TPV; ++v) p[v] = xs[v * 9 + i] * ys[v * 9 + j];
                    #pragma unroll
                    for (int c = 0; c < 3; ++c) {
                        if (ALLOWC[a][b] & (1 << c)) {
                            #pragma unroll
                            for (int dk = 0; dk < 2 * c + 1; ++dk) {
                                const int k = c * c + dk;
                                float cv = Cl[(i * 9 + j) * 9 + k];
                                #pragma unroll
                                for (int v = 0; v < TPV; ++v) os[v * 9 + k] += cv * p[v];
                            }
                        }
                    }
                }
            }
        }
    }

    #pragma unroll
    for (int q = 0; q < 9 * TPV / 4; ++q) {
        float4 to;
        to.x = os[q * 4 + 0]; to.y = os[q * 4 + 1]; to.z = os[q * 4 + 2]; to.w = os[q * 4 + 3];
        o4[q] = to;
    }
}

// ---------------------------------------------------------------------------

extern "C" void kernel_launch(void* const* d_in, const int* in_sizes, int n_in,
                              void* d_out, int out_size, void* d_ws, size_t ws_size,
                              hipStream_t stream) {
    const float* x   = (const float*)d_in[0];
    const float* y   = (const float*)d_in[1];
    const float* tpw = (const float*)d_in[2];
    const float* Wfx = (const float*)d_in[3];
    const float* bfx = (const float*)d_in[4];
    const float* Wfy = (const float*)d_in[5];
    const float* bfy = (const float*)d_in[6];
    float* out = (float*)d_out;
    float* Cd = (float*)d_ws;   // 729 floats

    hipLaunchKernelGGL(setup_C_kernel, dim3(1), dim3(64), 0, stream, tpw, Cd);

    long n_items = (long)out_size / 9;              // E*CH = 16777216
    long n_sets = (n_items + TPV - 1) / TPV;        // 4194304
    int block = 256;
    long grid = (n_sets + block - 1) / block;       // 16384

    hipLaunchKernelGGL(tp_main_kernel, dim3((unsigned)grid), dim3(block), 0, stream,
                       x, y, out, Cd, Wfx, bfx, Wfy, bfy, n_items);
}